// Round 1
// baseline (1233.586 us; speedup 1.0000x reference)
//
#include <hip/hip_runtime.h>
#include <math.h>

typedef __attribute__((ext_vector_type(8))) short short8;
typedef __attribute__((ext_vector_type(4))) float floatx4;
typedef __attribute__((ext_vector_type(4))) _Float16 half4;

__device__ __forceinline__ unsigned short f2bf(float f) {
    unsigned u = __builtin_bit_cast(unsigned, f);
    u += 0x7FFFu + ((u >> 16) & 1u);   // RNE
    return (unsigned short)(u >> 16);
}

// ---------------------------------------------------------------------------
// R7: weights are pre-converted ONCE per launch into bf16 tiles laid out in
// the EXACT swizzled LDS image (tile[row][g*8+j] = bf16 A[gm][k0+(g^(row&7))*8+j]),
// so conv A-staging is 2*MT async global_load_lds_dwordx4 per thread instead of
// ~130 VALU insts of fp32 load + f2bf + repack per k-step (Common-mistake #1).
// ---------------------------------------------------------------------------
#define NWT 10
struct PrepAll {
    const float* src[NWT];
    unsigned int dstOff[NWT];   // ushort offset into wprep (== startG*8)
    int M[NWT], Ktot[NWT], KT[NWT], Mblk[NWT];
    int startG[NWT + 1];        // granule (short8) prefix sums
};

__global__ __launch_bounds__(256) void prep_all_k(PrepAll d, unsigned short* __restrict__ P)
{
    const int t = blockIdx.x * 256 + threadIdx.x;
    if (t >= d.startG[NWT]) return;
    int wi = 0;
#pragma unroll
    for (int i = 1; i < NWT; ++i) wi += (t >= d.startG[i]);
    const int g8   = t - d.startG[wi];
    const int Mblk = d.Mblk[wi];
    const int ksC  = d.KT[wi] >> 6;
    const int g    = g8 & 7;
    int rest = g8 >> 3;
    const int row = rest % Mblk; rest /= Mblk;
    const int ks  = rest % ksC;
    const int mb  = rest / ksC;
    const int kchunk = g ^ (row & 7);
    const int gm  = mb * Mblk + row;
    const int M = d.M[wi], Ktot = d.Ktot[wi];
    const float* __restrict__ src = d.src[wi];
    short8 v;
#pragma unroll
    for (int j = 0; j < 8; ++j) {
        int gk = ks * 64 + kchunk * 8 + j;
        float f = (gm < M && gk < Ktot) ? src[(size_t)gm * Ktot + gk] : 0.f;
        v[j] = (short)f2bf(f);
    }
    *(short8*)(P + d.dstOff[wi] + (size_t)g8 * 8) = v;
}

// Implicit-GEMM conv on bf16 MFMA: Out[z][m][n] = sum_k A[m][k]*B(k,n) + bias[m]
// MODE 0: zero-pad im2col  MODE 1: reflect-pad im2col  MODE 2: deform bilinear*sigmoid(mask)
// Tile: BM=64*MT, BN=64, BK=64. 256 threads = 4 waves.
// A comes from pre-swizzled bf16 tiles (see prep_all_k): tile index
// (blockIdx.y * KT/64 + k0/64), staged via async global_load_lds (issued before
// the B-gather phase so the DMA hides under gather VALU; __syncthreads drains).
// B-stage is n-major: lane = n, so gathers for a fixed (ci,r) are consecutive
// across lanes (line-shared). Deform meta is a packed base index (independently
// clamped corners + step bits) + mask-premultiplied half4 weights:
//   packed = (yc0*W+xc0) | (xc1-xc0)<<24 | (yc1-yc0)<<25
// Corner addrs base, base+dx, base+dy*W, base+dy*W+dx are the EXACT clamped
// corners for every in/out-of-bounds combination (OOB corners carry weight 0).
template<int CIN,int KH,int KW,int STR,int PAD,int H,int W,int HO,int WO,int MODE,int MT>
__global__ __launch_bounds__(256) void conv_mfma(
    const unsigned short* __restrict__ Aprep, // pre-swizzled bf16 weight tiles
    const float* __restrict__ X,      // [Z][CIN][H][W]
    const float* __restrict__ OM,     // [Z][3*Kk][HO][WO] (deform only)
    const float* __restrict__ bias,   // [M]
    float* __restrict__ Out,          // [Z][M][HO*WO]
    int M)
{
    constexpr int Kk   = KH*KW;
    constexpr int Ktot = CIN*Kk;
    constexpr int HWc  = H*W;
    constexpr int HOWO = HO*WO;
    constexpr int KT   = (Ktot + 63) & ~63;
    constexpr int KSC  = KT >> 6;
    constexpr bool KGUARD = (Ktot % 64 != 0);
    constexpr bool META2  = (MODE == 2) && (Kk == 16);   // deform packed meta
    constexpr bool META01 = (MODE != 2);                 // gather-idx meta
    constexpr int KPAD = (Kk % 2 == 0) ? Kk + 1 : Kk;    // bank-friendly stride
    static_assert(KT % 64 == 0, "");

    const int z = blockIdx.z;
    const float* __restrict__ Xb  = X + (size_t)z * CIN * HWc;
    const float* __restrict__ OMb = (MODE == 2) ? (OM + (size_t)z * 3 * Kk * HOWO) : nullptr;
    float* __restrict__ Outb = Out + (size_t)z * (size_t)M * HOWO;

    const int n0   = blockIdx.x * 64;
    const int m0   = blockIdx.y * (64 * MT);
    const int tid  = threadIdx.x;
    const int lane = tid & 63;
    const int wave = tid >> 6;
    const int quad = lane >> 4;
    const int l16  = lane & 15;

    __shared__ unsigned short As[64 * MT][64];
    __shared__ unsigned short Bs[64][64];
    __shared__ int   MIb[META2 ? 64 * KPAD : 1];
    __shared__ half4 MWh[META2 ? 64 * KPAD : 1];
    __shared__ int   MI0[META01 ? 64 * KPAD : 1];

    // ---- precompute sampling metadata for the block's 64 n's x Kk taps
    if constexpr (META2) {
        for (int e = tid; e < 64 * Kk; e += 256) {
            int n = e / Kk, r = e - n * Kk;
            int gn = n0 + n, ho = gn / WO, wo = gn % WO;
            int ky = r / KW, kx = r % KW;
            float offy = OMb[(size_t)(2 * r) * HOWO + gn];
            float offx = OMb[(size_t)(2 * r + 1) * HOWO + gn];
            float ml   = OMb[(size_t)(2 * Kk + r) * HOWO + gn];
            float mask = 1.f / (1.f + expf(-ml));
            float ys = (float)(ho * STR - PAD + ky) + offy;
            float xs = (float)(wo * STR - PAD + kx) + offx;
            float y0f = floorf(ys), x0f = floorf(xs);
            float dy = ys - y0f, dx = xs - x0f;
            int y0 = (int)y0f, x0 = (int)x0f;
            int yc0 = min(max(y0, 0), H - 1);
            int yc1 = min(max(y0 + 1, 0), H - 1);
            int xc0 = min(max(x0, 0), W - 1);
            int xc1 = min(max(x0 + 1, 0), W - 1);
            bool y0ok = (y0 >= 0) & (y0 < H), y1ok = (y0 + 1 >= 0) & (y0 + 1 < H);
            bool x0ok = (x0 >= 0) & (x0 < W), x1ok = (x0 + 1 >= 0) & (x0 + 1 < W);
            half4 w;
            w[0] = (_Float16)((y0ok && x0ok) ? (1.f - dy) * (1.f - dx) * mask : 0.f);
            w[1] = (_Float16)((y0ok && x1ok) ? (1.f - dy) * dx * mask : 0.f);
            w[2] = (_Float16)((y1ok && x0ok) ? dy * (1.f - dx) * mask : 0.f);
            w[3] = (_Float16)((y1ok && x1ok) ? dy * dx * mask : 0.f);
            MIb[n * KPAD + r] = (yc0 * W + xc0) | ((xc1 - xc0) << 24) | ((yc1 - yc0) << 25);
            MWh[n * KPAD + r] = w;
        }
        __syncthreads();
    }
    if constexpr (META01) {
        for (int e = tid; e < 64 * Kk; e += 256) {
            int n = e / Kk, r = e - n * Kk;
            int gn = n0 + n, ho = gn / WO, wo = gn % WO;
            int ky = r / KW, kx = r % KW;
            int idx;
            if constexpr (MODE == 0) {
                int iy = ho * STR - PAD + ky;
                int ix = wo * STR - PAD + kx;
                idx = (iy >= 0 && iy < H && ix >= 0 && ix < W) ? iy * W + ix : -1;
            } else {
                int iy = ho - PAD + ky; iy = iy < 0 ? -iy : (iy >= H ? 2 * H - 2 - iy : iy);
                int ix = wo - PAD + kx; ix = ix < 0 ? -ix : (ix >= W ? 2 * W - 2 - ix : ix);
                idx = iy * W + ix;
            }
            MI0[n * KPAD + r] = idx;
        }
        __syncthreads();
    }

    floatx4 acc[MT][4];
#pragma unroll
    for (int s = 0; s < MT; ++s)
#pragma unroll
        for (int t = 0; t < 4; ++t) acc[s][t] = (floatx4){0.f, 0.f, 0.f, 0.f};

    // staging maps (B)
    const int bn2 = tid & 63;   // B: n (lane) -> coalesced gathers
    const int bkc = tid >> 6;   // B: 16-k chunk (0..3)
    const int gn2 = n0 + bn2;
    const int ho2 = gn2 / WO, wo2 = gn2 % WO;

    for (int k0 = 0; k0 < KT; k0 += 64) {
        // ---- stage A tile(s): async DMA from pre-swizzled bf16 tiles.
        // Issued FIRST so the loads fly under the B-gather VALU work below.
        {
            const unsigned short* At =
                Aprep + ((size_t)blockIdx.y * KSC + (k0 >> 6)) * (size_t)(64 * MT * 64);
#pragma unroll
            for (int c = 0; c < 2 * MT; ++c) {
                const int chunk = c * 4 + wave;   // 1 KiB per wave-chunk
                __builtin_amdgcn_global_load_lds(
                    (const __attribute__((address_space(1))) void*)(At + (size_t)chunk * 512 + lane * 8),
                    (__attribute__((address_space(3))) void*)(&As[0][0] + chunk * 512),
                    16, 0, 0);
            }
        }

        // ---- stage B tile (sampled -> bf16 LDS), n-major
        {
            unsigned short tmp[16];
            if constexpr (META2) {
                // Kk==16: ci fixed for this thread's 16-k chunk
                const int ci = (k0 >> 4) + bkc;
                const float* img = Xb + (size_t)ci * HWc;
#pragma unroll
                for (int j = 0; j < 16; ++j) {
                    int packed = MIb[bn2 * KPAD + j];
                    half4 w    = MWh[bn2 * KPAD + j];
                    int base = packed & 0xFFFFFF;
                    int dxs  = (packed >> 24) & 1;
                    int dys  = ((packed >> 25) & 1) ? W : 0;
                    float v = (float)w[0] * img[base]
                            + (float)w[1] * img[base + dxs]
                            + (float)w[2] * img[base + dys]
                            + (float)w[3] * img[base + dys + dxs];
                    tmp[j] = f2bf(v);
                }
            } else if constexpr (META01) {
#pragma unroll
                for (int j = 0; j < 16; ++j) {
                    int gk = k0 + bkc * 16 + j;
                    float v = 0.f;
                    if (!KGUARD || gk < Ktot) {
                        int ci, r;
                        if constexpr (Kk == 16) { ci = gk >> 4; r = gk & 15; }
                        else { ci = gk / Kk; r = gk - ci * Kk; }
                        int idx = MI0[bn2 * KPAD + r];
                        if (MODE == 1 || idx >= 0)
                            v = Xb[(size_t)ci * HWc + idx];
                    }
                    tmp[j] = f2bf(v);
                }
            } else {
                // direct deform path (stage 1: Kk=49, meta too large for LDS)
#pragma unroll 4
                for (int j = 0; j < 16; ++j) {
                    int gk = k0 + bkc * 16 + j;
                    float v = 0.f;
                    if (!KGUARD || gk < Ktot) {
                        int ci = gk / Kk;
                        int r  = gk - ci * Kk;
                        int ky = r / KW, kx = r % KW;
                        const float* img = Xb + (size_t)ci * HWc;
                        float offy = OMb[(size_t)(2 * r) * HOWO + gn2];
                        float offx = OMb[(size_t)(2 * r + 1) * HOWO + gn2];
                        float ml   = OMb[(size_t)(2 * Kk + r) * HOWO + gn2];
                        float mask = 1.f / (1.f + expf(-ml));
                        float ys = (float)(ho2 * STR - PAD + ky) + offy;
                        float xs = (float)(wo2 * STR - PAD + kx) + offx;
                        float y0f = floorf(ys), x0f = floorf(xs);
                        float dy = ys - y0f, dx = xs - x0f;
                        int y0 = (int)y0f, x0 = (int)x0f;
                        float v00 = 0.f, v01 = 0.f, v10 = 0.f, v11 = 0.f;
                        bool y0ok = (y0 >= 0) & (y0 < H), y1ok = (y0 + 1 >= 0) & (y0 + 1 < H);
                        bool x0ok = (x0 >= 0) & (x0 < W), x1ok = (x0 + 1 >= 0) & (x0 + 1 < W);
                        if (y0ok && x0ok) v00 = img[y0 * W + x0];
                        if (y0ok && x1ok) v01 = img[y0 * W + x0 + 1];
                        if (y1ok && x0ok) v10 = img[(y0 + 1) * W + x0];
                        if (y1ok && x1ok) v11 = img[(y0 + 1) * W + x0 + 1];
                        v = (v00 * (1.f - dy) * (1.f - dx) + v01 * (1.f - dy) * dx +
                             v10 * dy * (1.f - dx) + v11 * dy * dx) * mask;
                    }
                    tmp[j] = f2bf(v);
                }
            }
            short8 s0, s1;
#pragma unroll
            for (int j = 0; j < 8; ++j) { s0[j] = (short)tmp[j]; s1[j] = (short)tmp[8 + j]; }
            const int g0 = (bkc * 2)     ^ (bn2 & 7);
            const int g1 = (bkc * 2 + 1) ^ (bn2 & 7);
            *(short8*)&Bs[bn2][g0 * 8] = s0;
            *(short8*)&Bs[bn2][g1 * 8] = s1;
        }
        __syncthreads();   // drains vmcnt (DMA) + lgkmcnt before MFMA reads

        // ---- MFMA: wave computes MT x 16(m) x 64(n), K=64
        {
            const int mrow = wave * 16 + l16;
#pragma unroll
            for (int kk = 0; kk < 2; ++kk) {
                const int kg = kk * 4 + quad;
                short8 a[MT];
#pragma unroll
                for (int s = 0; s < MT; ++s)
                    a[s] = *(const short8*)&As[s * 64 + mrow][((kg ^ (mrow & 7)) * 8)];
#pragma unroll
                for (int t = 0; t < 4; ++t) {
                    const int ncol = t * 16 + l16;
                    short8 b = *(const short8*)&Bs[ncol][((kg ^ (ncol & 7)) * 8)];
#pragma unroll
                    for (int s = 0; s < MT; ++s)
                        acc[s][t] = __builtin_amdgcn_mfma_f32_16x16x32_bf16(a[s], b, acc[s][t], 0, 0, 0);
                }
            }
        }
        __syncthreads();
    }

    // ---- epilogue: bias + store. D layout: row = quad*4+i, col = lane&15
#pragma unroll
    for (int s = 0; s < MT; ++s) {
#pragma unroll
        for (int t = 0; t < 4; ++t) {
            const int ng = n0 + t * 16 + l16;
#pragma unroll
            for (int i = 0; i < 4; ++i) {
                int mg = m0 + s * 64 + wave * 16 + quad * 4 + i;
                if (mg < M)
                    Outb[(size_t)mg * HOWO + ng] = acc[s][t][i] + bias[mg];
            }
        }
    }
}

// Instance norm over HW per (b,c) block; optional ReLU, dual-write, add-into-out.
template<bool RELU, bool DUAL, bool ADDIN>
__global__ __launch_bounds__(256) void instnorm_k(
    const float* __restrict__ in, float* __restrict__ out,
    float* __restrict__ out2, int HW)
{
    const int bc = blockIdx.x;
    const float* p = in + (size_t)bc * HW;
    float s = 0.f, ss = 0.f;
    for (int i = threadIdx.x; i < HW; i += 256) { float v = p[i]; s += v; ss += v * v; }
    __shared__ float rs[256], rq[256];
    rs[threadIdx.x] = s; rq[threadIdx.x] = ss;
    __syncthreads();
    for (int o = 128; o > 0; o >>= 1) {
        if (threadIdx.x < o) { rs[threadIdx.x] += rs[threadIdx.x + o]; rq[threadIdx.x] += rq[threadIdx.x + o]; }
        __syncthreads();
    }
    float mean = rs[0] / (float)HW;
    float var  = rq[0] / (float)HW - mean * mean;
    float inv  = rsqrtf(var + 1e-5f);
    float* q  = out + (size_t)bc * HW;
    float* q2 = DUAL ? (out2 + (size_t)bc * HW) : nullptr;
    for (int i = threadIdx.x; i < HW; i += 256) {
        float v = (p[i] - mean) * inv;
        if (RELU) v = fmaxf(v, 0.f);
        if (ADDIN) {
            q[i] = q[i] + v;
        } else {
            q[i] = v;
            if (DUAL) q2[i] = v;
        }
    }
}

extern "C" void kernel_launch(void* const* d_in, const int* in_sizes, int n_in,
                              void* d_out, int out_size, void* d_ws, size_t ws_size,
                              hipStream_t stream)
{
    const float* x      = (const float*)d_in[0];
    const float* w_off1 = (const float*)d_in[1];
    const float* b_off1 = (const float*)d_in[2];
    const float* w1     = (const float*)d_in[3];
    const float* b1     = (const float*)d_in[4];
    const float* w_off2 = (const float*)d_in[5];
    const float* b_off2 = (const float*)d_in[6];
    const float* w2     = (const float*)d_in[7];
    const float* b2     = (const float*)d_in[8];
    const float* w_off3 = (const float*)d_in[9];
    const float* b_off3 = (const float*)d_in[10];
    const float* w3     = (const float*)d_in[11];
    const float* b3     = (const float*)d_in[12];
    const float* rwa[2] = {(const float*)d_in[13], (const float*)d_in[17]};
    const float* rba[2] = {(const float*)d_in[14], (const float*)d_in[18]};
    const float* rwb[2] = {(const float*)d_in[15], (const float*)d_in[19]};
    const float* rbb[2] = {(const float*)d_in[16], (const float*)d_in[20]};

    float* out   = (float*)d_out;
    float* h_out = out;                         // [16,256,32,32]
    float* skip2 = out + 4194304;               // [16,128,64,64]
    float* skip3 = out + 4194304 + 8388608;     // [16,256,32,32]

    // workspace layout (floats). pool regions are time-multiplexed:
    //   om1  (stage 1):   pool[0        .. 9,633,792)
    //   om2  (stage 2):   pool[0        .. 3,145,728)
    //   om3  (stage 3):   pool[3,145,728.. 3,932,160)
    //   y1   (residual):  pool[0        .. 4,194,304)
    //   y2   (residual):  pool[4,194,304.. 8,388,608)
    //   wprep (whole launch, bf16): pool[9,633,792 .. 11,270,144)  (3,272,704 ushorts)
    // total = 16,777,216 + 11,270,144 floats = 112.2 MB (< previous 116.4 MB)
    float* wsf  = (float*)d_ws;
    float* h1   = wsf;                      // 16,777,216  [16,64,128,128]
    float* pool = h1 + 16777216;
    float* om1  = pool;
    float* om2  = pool;
    float* om3  = pool + 3145728;
    float* y1   = pool;
    float* y2   = pool + 4194304;
    unsigned short* wprep = (unsigned short*)(pool + 9633792);

    // ---- Weight prep: fp32 -> bf16, pre-swizzled into LDS tile image (one launch)
    {
        PrepAll pd;
        const float* srcs[NWT] = {w_off1, w1, w_off2, w2, w_off3, w3,
                                  rwa[0], rwb[0], rwa[1], rwb[1]};
        const int Ms [NWT] = {147, 64, 48, 128, 48, 256, 256, 256, 256, 256};
        const int Kts[NWT] = {147, 147, 1024, 1024, 2048, 2048, 2304, 2304, 2304, 2304};
        const int KTs[NWT] = {192, 192, 1024, 1024, 2048, 2048, 2304, 2304, 2304, 2304};
        const int Mbs[NWT] = {128, 64, 64, 128, 64, 128, 128, 128, 128, 128};
        int sg = 0;
        pd.startG[0] = 0;
        for (int i = 0; i < NWT; ++i) {
            pd.src[i] = srcs[i];
            pd.M[i] = Ms[i]; pd.Ktot[i] = Kts[i]; pd.KT[i] = KTs[i]; pd.Mblk[i] = Mbs[i];
            pd.dstOff[i] = (unsigned)sg * 8u;
            int mb = (Ms[i] + Mbs[i] - 1) / Mbs[i];
            sg += mb * (KTs[i] >> 6) * Mbs[i] * 8;
            pd.startG[i + 1] = sg;
        }
        // sg == 409,088 granules == 3,272,704 ushorts
        prep_all_k<<<dim3((sg + 255) / 256), 256, 0, stream>>>(pd, wprep);
    }
    // prepped-weight tile offsets (ushorts) — must match the loop above
    const unsigned short* pw_off1 = wprep + 0;
    const unsigned short* pw1     = wprep + 49152;
    const unsigned short* pw_off2 = wprep + 61440;
    const unsigned short* pw2     = wprep + 126976;
    const unsigned short* pw_off3 = wprep + 258048;
    const unsigned short* pw3     = wprep + 389120;
    const unsigned short* prwa[2] = {wprep + 913408,  wprep + 2093056};
    const unsigned short* prwb[2] = {wprep + 1503232, wprep + 2682880};

    // ---- Stage 1: 7x7 s1 p3, Cin=3 -> 64ch @128x128 (4-batch chunks to bound om1)
    for (int c = 0; c < 4; ++c) {
        const float* xc = x + (size_t)c * 4 * 3 * 16384;
        conv_mfma<3,7,7,1,3,128,128,128,128,0,2><<<dim3(256, 2, 4), 256, 0, stream>>>(
            pw_off1, xc, nullptr, b_off1, om1, 147);
        conv_mfma<3,7,7,1,3,128,128,128,128,2,1><<<dim3(256, 1, 4), 256, 0, stream>>>(
            pw1, xc, om1, b1, h1 + (size_t)c * 4 * 64 * 16384, 64);
    }
    instnorm_k<true,false,false><<<16 * 64, 256, 0, stream>>>(h1, h1, nullptr, 16384);

    // ---- Stage 2: 4x4 s2 p1, 64 -> 128ch @64x64
    conv_mfma<64,4,4,2,1,128,128,64,64,0,1><<<dim3(64, 1, 16), 256, 0, stream>>>(
        pw_off2, h1, nullptr, b_off2, om2, 48);
    conv_mfma<64,4,4,2,1,128,128,64,64,2,2><<<dim3(64, 1, 16), 256, 0, stream>>>(
        pw2, h1, om2, b2, skip2, 128);
    instnorm_k<true,false,false><<<16 * 128, 256, 0, stream>>>(skip2, skip2, nullptr, 4096);

    // ---- Stage 3: 4x4 s2 p1, 128 -> 256ch @32x32
    conv_mfma<128,4,4,2,1,64,64,32,32,0,1><<<dim3(16, 1, 16), 256, 0, stream>>>(
        pw_off3, skip2, nullptr, b_off3, om3, 48);
    conv_mfma<128,4,4,2,1,64,64,32,32,2,2><<<dim3(16, 2, 16), 256, 0, stream>>>(
        pw3, skip2, om3, b3, skip3, 256);
    instnorm_k<true,true,false><<<16 * 256, 256, 0, stream>>>(skip3, skip3, h_out, 1024);

    // ---- Residual blocks: reflect-pad 3x3, 256 -> 256 @32x32
    for (int r = 0; r < 2; ++r) {
        conv_mfma<256,3,3,1,1,32,32,32,32,1,2><<<dim3(16, 2, 16), 256, 0, stream>>>(
            prwa[r], h_out, nullptr, rba[r], y1, 256);
        instnorm_k<true,false,false><<<16 * 256, 256, 0, stream>>>(y1, y1, nullptr, 1024);
        conv_mfma<256,3,3,1,1,32,32,32,32,1,2><<<dim3(16, 2, 16), 256, 0, stream>>>(
            prwb[r], y1, nullptr, rbb[r], y2, 256);
        instnorm_k<false,false,true><<<16 * 256, 256, 0, stream>>>(y2, h_out, nullptr, 1024);
    }
}